// Round 1
// baseline (1515.766 us; speedup 1.0000x reference)
//
#include <hip/hip_runtime.h>
#include <hip/hip_bf16.h>

#define D_MODEL 1024
#define N_HEADS 16
#define D_HEAD  64
#define ROT_DIM 32
#define BATCH   4
#define SEQ     4096
#define BS      (BATCH*SEQ)     // 16384
#define QKV_N   (3*D_MODEL)     // 3072
#define NCHUNK  8
#define CH_S    (SEQ/NCHUNK)    // 512

// ---- storage type helpers (fp32 or bf16 workspace) ----
template<typename T> __device__ inline float ldv(const T* p);
template<> __device__ inline float ldv<float>(const float* p){ return *p; }
template<> __device__ inline float ldv<__hip_bfloat16>(const __hip_bfloat16* p){ return __bfloat162float(*p); }
template<typename T> __device__ inline void stv(T* p, float v);
template<> __device__ inline void stv<float>(float* p, float v){ *p = v; }
template<> __device__ inline void stv<__hip_bfloat16>(__hip_bfloat16* p, float v){ *p = __float2bfloat16(v); }

// ---------------- K1: qkv = x @ W^T + b  (M=16384, N=3072, K=1024) ----------------
template<typename T>
__global__ __launch_bounds__(256)
void qkv_gemm(const float* __restrict__ x, const float* __restrict__ W,
              const float* __restrict__ bias, T* __restrict__ qkv)
{
    __shared__ float As[16][68];
    __shared__ float Bs[16][68];
    const int t  = threadIdx.x;
    const int tx = t & 15, ty = t >> 4;
    const int row0 = blockIdx.y * 64;   // M tile
    const int col0 = blockIdx.x * 64;   // N tile
    const int lr = t >> 2;              // 0..63
    const int lc = t & 3;               // float4 slot along K

    float acc[4][4] = {};

    for (int k0 = 0; k0 < D_MODEL; k0 += 16) {
        float4 av = *(const float4*)&x[(size_t)(row0 + lr) * D_MODEL + k0 + lc*4];
        float4 bv = *(const float4*)&W[(size_t)(col0 + lr) * D_MODEL + k0 + lc*4];
        __syncthreads();
        As[lc*4+0][lr] = av.x; As[lc*4+1][lr] = av.y;
        As[lc*4+2][lr] = av.z; As[lc*4+3][lr] = av.w;
        Bs[lc*4+0][lr] = bv.x; Bs[lc*4+1][lr] = bv.y;
        Bs[lc*4+2][lr] = bv.z; Bs[lc*4+3][lr] = bv.w;
        __syncthreads();
        #pragma unroll
        for (int kk = 0; kk < 16; ++kk) {
            float4 a4 = *(const float4*)&As[kk][ty*4];
            float4 b4 = *(const float4*)&Bs[kk][tx*4];
            float a[4] = {a4.x, a4.y, a4.z, a4.w};
            float b[4] = {b4.x, b4.y, b4.z, b4.w};
            #pragma unroll
            for (int i = 0; i < 4; ++i)
                #pragma unroll
                for (int j = 0; j < 4; ++j)
                    acc[i][j] += a[i] * b[j];
        }
    }

    const int r = row0 + ty*4;
    const int c = col0 + tx*4;
    float bb[4] = {bias[c], bias[c+1], bias[c+2], bias[c+3]};
    #pragma unroll
    for (int i = 0; i < 4; ++i)
        #pragma unroll
        for (int j = 0; j < 4; ++j)
            stv(&qkv[(size_t)(r+i)*QKV_N + c + j], acc[i][j] + bb[j]);
}

// ---------------- K2: in-place RoPE on q,k (only s<32; pairs along s) ----------------
template<typename T>
__global__ __launch_bounds__(256)
void rope_kernel(T* __restrict__ qkv)
{
    int tid = blockIdx.x * 256 + threadIdx.x;   // 2*16*4*64*16 = 131072 total
    int m  = tid & 15;          // freq index (pair m -> s = 2m, 2m+1)
    int d  = (tid >> 4) & 63;   // position (along dh axis!)
    int b  = (tid >> 10) & 3;
    int h  = (tid >> 12) & 15;
    int qk = tid >> 16;         // 0 = q, 1 = k

    float invf = powf(10000.0f, -(float)m / 16.0f);
    float f = (float)d * invf;
    float cs = cosf(f), sn = sinf(f);

    size_t base = (size_t)b * SEQ * QKV_N + (size_t)h * 192 + (size_t)qk * 64 + d;
    T* p0 = qkv + base + (size_t)(2*m)   * QKV_N;
    T* p1 = qkv + base + (size_t)(2*m+1) * QKV_N;
    float e0 = ldv(p0), e1 = ldv(p1);
    stv(p0, e0*cs - e1*sn);
    stv(p1, e1*cs + e0*sn);
}

// ---------------- K3: partial scores[d][e] = sum_{s in chunk} q[d,s]*k[e,s] ----------------
template<typename T>
__global__ __launch_bounds__(256)
void scores_partial(const T* __restrict__ qkv, float* __restrict__ partial)
{
    __shared__ float SA[64][68];
    __shared__ float SB[64][68];
    const int t = threadIdx.x, tx = t & 15, ty = t >> 4;
    const int hb = blockIdx.x, chunk = blockIdx.y;
    const int h = hb >> 2, b = hb & 3;
    const T* qb = qkv + (size_t)b * SEQ * QKV_N + (size_t)h * 192;
    const int d_l = t & 63, si0 = t >> 6;

    float acc[4][4] = {};

    for (int s0 = chunk * CH_S; s0 < (chunk + 1) * CH_S; s0 += 64) {
        __syncthreads();
        #pragma unroll
        for (int k = 0; k < 16; ++k) {
            int si = si0 + k*4;
            const T* row = qb + (size_t)(s0 + si) * QKV_N;
            SA[si][d_l] = ldv(row + d_l);        // q[d, s]
            SB[si][d_l] = ldv(row + 64 + d_l);   // k[e, s]
        }
        __syncthreads();
        for (int si = 0; si < 64; ++si) {
            float4 a4 = *(const float4*)&SA[si][ty*4];
            float4 b4 = *(const float4*)&SB[si][tx*4];
            float a[4] = {a4.x, a4.y, a4.z, a4.w};
            float b2[4] = {b4.x, b4.y, b4.z, b4.w};
            #pragma unroll
            for (int i = 0; i < 4; ++i)
                #pragma unroll
                for (int j = 0; j < 4; ++j)
                    acc[i][j] += a[i] * b2[j];
        }
    }

    float* pb = partial + ((size_t)hb * NCHUNK + chunk) * 4096;
    #pragma unroll
    for (int i = 0; i < 4; ++i)
        #pragma unroll
        for (int j = 0; j < 4; ++j)
            pb[(ty*4 + i) * 64 + tx*4 + j] = acc[i][j];
}

// ---------------- K4: reduce partials, scale, softmax over e; write P^T[e][d] ----------------
__global__ __launch_bounds__(64)
void softmax_k(const float* __restrict__ partial, float* __restrict__ Pt)
{
    __shared__ float L[64][65];
    const int d = threadIdx.x;
    const int hb = blockIdx.x;
    const float* pb = partial + (size_t)hb * NCHUNK * 4096;

    float mx = -1e30f;
    for (int e = 0; e < 64; ++e) {
        float s = 0.f;
        #pragma unroll
        for (int c = 0; c < NCHUNK; ++c) s += pb[c*4096 + d*64 + e];
        s *= 0.125f;   // D_HEAD^-0.5
        L[d][e] = s;
        mx = fmaxf(mx, s);
    }
    float sum = 0.f;
    for (int e = 0; e < 64; ++e) { float v = expf(L[d][e] - mx); L[d][e] = v; sum += v; }
    float inv = 1.f / sum;
    float* pt = Pt + (size_t)hb * 4096;
    for (int e = 0; e < 64; ++e) pt[e*64 + d] = L[d][e] * inv;   // P^T: [e][d]
}

// ---------------- K5: out[h,d,b,s] = sum_e P[d,e] * v[e,s] ----------------
template<typename T>
__global__ __launch_bounds__(256)
void attn_out(const T* __restrict__ qkv, const float* __restrict__ Pt,
              float* __restrict__ out)
{
    __shared__ float SP[64][68];   // SP[e][d]
    __shared__ float SV[64][68];   // SV[e][si]
    const int t = threadIdx.x, tx = t & 15, ty = t >> 4;
    const int hb = blockIdx.x, chunk = blockIdx.y;
    const int h = hb >> 2, b = hb & 3;

    #pragma unroll
    for (int i = 0; i < 16; ++i) {
        int idx = i*256 + t;
        SP[idx >> 6][idx & 63] = Pt[(size_t)hb * 4096 + idx];
    }

    const T* vb = qkv + (size_t)b * SEQ * QKV_N + (size_t)h * 192 + 128;
    const int e_l = t & 63, si0 = t >> 6;

    for (int s0 = chunk * CH_S; s0 < (chunk + 1) * CH_S; s0 += 64) {
        __syncthreads();
        #pragma unroll
        for (int k = 0; k < 16; ++k) {
            int si = si0 + k*4;
            SV[e_l][si] = ldv(vb + (size_t)(s0 + si) * QKV_N + e_l);
        }
        __syncthreads();
        float o[4][4] = {};
        for (int e = 0; e < 64; ++e) {
            float4 p4 = *(const float4*)&SP[e][ty*4];
            float4 v4 = *(const float4*)&SV[e][tx*4];
            float p[4] = {p4.x, p4.y, p4.z, p4.w};
            float v[4] = {v4.x, v4.y, v4.z, v4.w};
            #pragma unroll
            for (int i = 0; i < 4; ++i)
                #pragma unroll
                for (int j = 0; j < 4; ++j)
                    o[i][j] += p[i] * v[j];
        }
        #pragma unroll
        for (int i = 0; i < 4; ++i) {
            float4 w4 = make_float4(o[i][0], o[i][1], o[i][2], o[i][3]);
            size_t oidx = (((size_t)h*64 + ty*4 + i)*4 + b) * SEQ + s0 + tx*4;
            *(float4*)&out[oidx] = w4;
        }
    }
}

// ---------------- launcher ----------------
template<typename T>
static void run_all(const float* x, const float* W, const float* bias,
                    float* out, void* ws, hipStream_t stream)
{
    T* qkv = (T*)ws;
    float* partial = (float*)((char*)ws + (size_t)BS * QKV_N * sizeof(T));
    float* Pt = partial + (size_t)64 * NCHUNK * 4096;

    qkv_gemm<T><<<dim3(QKV_N/64, BS/64), 256, 0, stream>>>(x, W, bias, qkv);
    rope_kernel<T><<<512, 256, 0, stream>>>(qkv);
    scores_partial<T><<<dim3(64, NCHUNK), 256, 0, stream>>>(qkv, partial);
    softmax_k<<<64, 64, 0, stream>>>(partial, Pt);
    attn_out<T><<<dim3(64, NCHUNK), 256, 0, stream>>>(qkv, Pt, out);
}

extern "C" void kernel_launch(void* const* d_in, const int* in_sizes, int n_in,
                              void* d_out, int out_size, void* d_ws, size_t ws_size,
                              hipStream_t stream)
{
    const float* x    = (const float*)d_in[0];
    const float* W    = (const float*)d_in[1];
    const float* bias = (const float*)d_in[2];
    float* out = (float*)d_out;

    const size_t qkv_elems = (size_t)BS * QKV_N;
    const size_t extra = ((size_t)64 * NCHUNK * 4096 + (size_t)64 * 4096) * sizeof(float);
    const size_t need_f32 = qkv_elems * sizeof(float) + extra;

    if (ws_size >= need_f32)
        run_all<float>(x, W, bias, out, d_ws, stream);
    else
        run_all<__hip_bfloat16>(x, W, bias, out, d_ws, stream);
}

// Round 3
// 477.205 us; speedup vs baseline: 3.1763x; 3.1763x over previous
//
#include <hip/hip_runtime.h>
#include <hip/hip_bf16.h>
#include <stdint.h>

#define D_MODEL 1024
#define N_HEADS 16
#define D_HEAD  64
#define BATCH   4
#define SEQ     4096
#define BS      (BATCH*SEQ)     // 16384
#define QKV_N   (3*D_MODEL)     // 3072
#define NCHUNK  8
#define CH_S    (SEQ/NCHUNK)    // 512

using f16x8 = __attribute__((ext_vector_type(8))) _Float16;
using f32x4 = __attribute__((ext_vector_type(4))) float;

__device__ static inline ushort f2h(float f) {
    _Float16 h = (_Float16)f; ushort u; __builtin_memcpy(&u, &h, 2); return u;
}
__device__ static inline float h2f(ushort u) {
    _Float16 h; __builtin_memcpy(&h, &u, 2); return (float)h;
}
__device__ static inline void async16(const ushort* g, ushort* l) {
    __builtin_amdgcn_global_load_lds(
        (const __attribute__((address_space(1))) void*)g,
        (__attribute__((address_space(3))) void*)l, 16, 0, 0);
}

// ---------------- K0a: x -> fp16 hi (+ optional fp16 residual lo) ----------------
__global__ __launch_bounds__(256)
void cvt_x_f16(const float* __restrict__ in, ushort* __restrict__ hi,
               ushort* __restrict__ lo, int write_lo)
{
    int i = (blockIdx.x * 256 + threadIdx.x) * 8;
    float4 a = *(const float4*)(in + i);
    float4 b = *(const float4*)(in + i + 4);
    float f[8] = {a.x,a.y,a.z,a.w,b.x,b.y,b.z,b.w};
    ushort h[8];
    #pragma unroll
    for (int j = 0; j < 8; ++j) h[j] = f2h(f[j]);
    *(ushort4*)(hi + i)     = make_ushort4(h[0],h[1],h[2],h[3]);
    *(ushort4*)(hi + i + 4) = make_ushort4(h[4],h[5],h[6],h[7]);
    if (write_lo) {
        ushort l[8];
        #pragma unroll
        for (int j = 0; j < 8; ++j) l[j] = f2h(f[j] - h2f(h[j]));
        *(ushort4*)(lo + i)     = make_ushort4(l[0],l[1],l[2],l[3]);
        *(ushort4*)(lo + i + 4) = make_ushort4(l[4],l[5],l[6],l[7]);
    }
}

// ---------------- K0b: W -> fp16 ----------------
__global__ __launch_bounds__(256)
void cvt_w_f16(const float* __restrict__ in, ushort* __restrict__ outp)
{
    int i = (blockIdx.x * 256 + threadIdx.x) * 8;
    float4 a = *(const float4*)(in + i);
    float4 b = *(const float4*)(in + i + 4);
    *(ushort4*)(outp + i)     = make_ushort4(f2h(a.x),f2h(a.y),f2h(a.z),f2h(a.w));
    *(ushort4*)(outp + i + 4) = make_ushort4(f2h(b.x),f2h(b.y),f2h(b.z),f2h(b.w));
}

// ---------------- K1: qkv GEMM via fp16 MFMA, fp32 acc, scatter epilogue ----------------
// A: x_hi (+x_lo phase 2) 16384x1024 f16 row-major; B: W 3072x1024 f16 row-major.
// q,k -> fp32 [h][b][ci][s]; v -> fp16 [h][b][ci][s].
__global__ __launch_bounds__(256)
void qkv_gemm_f16(const ushort* __restrict__ Ah, const ushort* __restrict__ Alo,
                  const ushort* __restrict__ Bh, const float* __restrict__ bias,
                  float* __restrict__ qarr, float* __restrict__ karr,
                  ushort* __restrict__ varr, int nphase)
{
    __shared__ ushort sA[128 * 32];   // 8 KB
    __shared__ ushort sB[128 * 32];   // 8 KB
    const int t = threadIdx.x;
    const int lane = t & 63, w = t >> 6;
    const int m0 = blockIdx.y * 128, n0 = blockIdx.x * 128;

    const int ar0 = (w*2 + 0) * 16 + (lane >> 2);
    const int ar1 = (w*2 + 1) * 16 + (lane >> 2);
    const int kc  = (lane & 3) * 8;
    const size_t aoff0 = (size_t)(m0 + ar0) * D_MODEL + kc;
    const size_t aoff1 = (size_t)(m0 + ar1) * D_MODEL + kc;
    const ushort* gB0base = Bh + (size_t)(n0 + ar0) * D_MODEL + kc;
    const ushort* gB1base = Bh + (size_t)(n0 + ar1) * D_MODEL + kc;
    ushort* lA0 = &sA[(w*2 + 0) * 512];
    ushort* lA1 = &sA[(w*2 + 1) * 512];
    ushort* lB0 = &sB[(w*2 + 0) * 512];
    ushort* lB1 = &sB[(w*2 + 1) * 512];

    const int wm = (w >> 1) * 64, wn = (w & 1) * 64;
    const int fr = lane & 15, fq = (lane >> 4) * 8;

    f32x4 acc[4][4] = {};

    for (int ph = 0; ph < nphase; ++ph) {
        const ushort* Ap = ph ? Alo : Ah;
        const ushort* gA0 = Ap + aoff0;
        const ushort* gA1 = Ap + aoff1;
        const ushort* gB0 = gB0base;
        const ushort* gB1 = gB1base;
        for (int k0 = 0; k0 < D_MODEL; k0 += 32) {
            __syncthreads();                       // previous tile consumed
            async16(gA0, lA0); async16(gA1, lA1);
            async16(gB0, lB0); async16(gB1, lB1);
            gA0 += 32; gA1 += 32; gB0 += 32; gB1 += 32;
            __syncthreads();                       // staged

            f16x8 af[4], bf[4];
            #pragma unroll
            for (int i = 0; i < 4; ++i)
                af[i] = *(const f16x8*)&sA[(wm + i*16 + fr) * 32 + fq];
            #pragma unroll
            for (int j = 0; j < 4; ++j)
                bf[j] = *(const f16x8*)&sB[(wn + j*16 + fr) * 32 + fq];
            #pragma unroll
            for (int i = 0; i < 4; ++i)
                #pragma unroll
                for (int j = 0; j < 4; ++j)
                    acc[i][j] = __builtin_amdgcn_mfma_f32_16x16x32_f16(
                                    af[i], bf[j], acc[i][j], 0, 0, 0);
        }
    }

    // epilogue: C/D row=(lane>>4)*4+r, col=lane&15 (verified mapping).
    // The wave's 64-column stripe (cgb..cgb+63) maps to exactly one (head, q/k/v).
    const int col = lane & 15, rq = (lane >> 4) * 4;
    const int cgb  = n0 + wn;            // 64-aligned
    const int h    = cgb / 192;
    const int type = (cgb % 192) / 64;   // 0=q, 1=k, 2=v
    const int b    = m0 >> 12;           // uniform per block
    const int sb   = (m0 & 4095) + wm;
    float* fdst = (type == 0) ? qarr : karr;

    #pragma unroll
    for (int j = 0; j < 4; ++j) {
        const int ci = j*16 + col;
        const float bj = bias[cgb + ci];
        const size_t rowoff = ((size_t)((h*4 + b)*64 + ci)) * SEQ;
        #pragma unroll
        for (int i = 0; i < 4; ++i) {
            const int s0 = sb + i*16 + rq;
            float v0 = acc[i][j][0] + bj, v1 = acc[i][j][1] + bj;
            float v2 = acc[i][j][2] + bj, v3 = acc[i][j][3] + bj;
            if (type < 2) {
                *(float4*)&fdst[rowoff + s0] = make_float4(v0, v1, v2, v3);
            } else {
                *(ushort4*)&varr[rowoff + s0] = make_ushort4(f2h(v0), f2h(v1), f2h(v2), f2h(v3));
            }
        }
    }
}

// ---------------- K2: in-place RoPE on q,k (pairs along s; only s<32) ----------------
__global__ __launch_bounds__(256)
void rope_kernel(float* __restrict__ qarr, float* __restrict__ karr)
{
    int tid = blockIdx.x * 256 + threadIdx.x;   // 131072 total
    int m  = tid & 15;          // freq index -> s pair (2m, 2m+1)
    int ci = (tid >> 4) & 63;   // position along dh axis
    int b  = (tid >> 10) & 3;
    int h  = (tid >> 12) & 15;
    float* base = (tid >> 16) ? karr : qarr;

    float invf = powf(10000.0f, -(float)m / 16.0f);
    float f = (float)ci * invf;
    float cs = cosf(f), sn = sinf(f);

    float* p = base + ((size_t)((h*4 + b)*64 + ci)) * SEQ + 2*m;
    float2 v = *(float2*)p;
    *(float2*)p = make_float2(v.x*cs - v.y*sn, v.y*cs + v.x*sn);
}

// ---------------- K3: partial scores[d][e] = sum_{s in chunk} q[d,s]*k[e,s] ----------------
__global__ __launch_bounds__(256)
void scores_partial(const float* __restrict__ qarr, const float* __restrict__ karr,
                    float* __restrict__ partial)
{
    __shared__ float SA[64][68];   // SA[si][d]
    __shared__ float SB[64][68];   // SB[si][e]
    const int t = threadIdx.x, tx = t & 15, ty = t >> 4;
    const int hb = blockIdx.x, chunk = blockIdx.y;
    const float* qb = qarr + (size_t)hb * 64 * SEQ;
    const float* kb = karr + (size_t)hb * 64 * SEQ;
    const int dl = t >> 2, sq = t & 3;

    float acc[4][4] = {};

    for (int s0 = chunk * CH_S; s0 < (chunk + 1) * CH_S; s0 += 64) {
        __syncthreads();
        #pragma unroll
        for (int r = 0; r < 4; ++r) {
            int si0 = sq*16 + r*4;
            float4 a4 = *(const float4*)&qb[(size_t)dl * SEQ + s0 + si0];
            float4 b4 = *(const float4*)&kb[(size_t)dl * SEQ + s0 + si0];
            SA[si0+0][dl] = a4.x; SA[si0+1][dl] = a4.y;
            SA[si0+2][dl] = a4.z; SA[si0+3][dl] = a4.w;
            SB[si0+0][dl] = b4.x; SB[si0+1][dl] = b4.y;
            SB[si0+2][dl] = b4.z; SB[si0+3][dl] = b4.w;
        }
        __syncthreads();
        for (int si = 0; si < 64; ++si) {
            float4 a4 = *(const float4*)&SA[si][ty*4];
            float4 b4 = *(const float4*)&SB[si][tx*4];
            float a[4] = {a4.x, a4.y, a4.z, a4.w};
            float b2[4] = {b4.x, b4.y, b4.z, b4.w};
            #pragma unroll
            for (int i = 0; i < 4; ++i)
                #pragma unroll
                for (int j = 0; j < 4; ++j)
                    acc[i][j] += a[i] * b2[j];
        }
    }

    float* pb = partial + ((size_t)hb * NCHUNK + chunk) * 4096;
    #pragma unroll
    for (int i = 0; i < 4; ++i)
        #pragma unroll
        for (int j = 0; j < 4; ++j)
            pb[(ty*4 + i) * 64 + tx*4 + j] = acc[i][j];
}

// ---------------- K4: reduce partials, scale, softmax over e; write P^T[e][d] ----------------
__global__ __launch_bounds__(64)
void softmax_k(const float* __restrict__ partial, float* __restrict__ Pt)
{
    __shared__ float L[64][65];
    const int d = threadIdx.x;
    const int hb = blockIdx.x;
    const float* pb = partial + (size_t)hb * NCHUNK * 4096;

    float mx = -1e30f;
    for (int e = 0; e < 64; ++e) {
        float s = 0.f;
        #pragma unroll
        for (int c = 0; c < NCHUNK; ++c) s += pb[c*4096 + d*64 + e];
        s *= 0.125f;
        L[d][e] = s;
        mx = fmaxf(mx, s);
    }
    float sum = 0.f;
    for (int e = 0; e < 64; ++e) { float v = expf(L[d][e] - mx); L[d][e] = v; sum += v; }
    float inv = 1.f / sum;
    float* pt = Pt + (size_t)hb * 4096;
    for (int e = 0; e < 64; ++e) pt[e*64 + d] = L[d][e] * inv;   // P^T: [e][d]
}

// ---------------- K5: out[h,d,b,s] = sum_e P[d,e] * v[e,s] ----------------
__global__ __launch_bounds__(256)
void attn_out(const ushort* __restrict__ varr, const float* __restrict__ Pt,
              float* __restrict__ out)
{
    __shared__ float SP[64][68];   // SP[e][d]
    __shared__ float SV[64][68];   // SV[e][si]
    const int t = threadIdx.x, tx = t & 15, ty = t >> 4;
    const int hb = blockIdx.x, chunk = blockIdx.y;
    const int h = hb >> 2, b = hb & 3;

    #pragma unroll
    for (int i = 0; i < 16; ++i) {
        int idx = i*256 + t;
        SP[idx >> 6][idx & 63] = Pt[(size_t)hb * 4096 + idx];
    }

    const ushort* vb = varr + (size_t)hb * 64 * SEQ;
    const int el = t >> 2, sq = t & 3;

    for (int s0 = chunk * CH_S; s0 < (chunk + 1) * CH_S; s0 += 64) {
        __syncthreads();
        #pragma unroll
        for (int r = 0; r < 4; ++r) {
            int si0 = sq*16 + r*4;
            ushort4 hv = *(const ushort4*)&vb[(size_t)el * SEQ + s0 + si0];
            SV[el][si0+0] = h2f(hv.x); SV[el][si0+1] = h2f(hv.y);
            SV[el][si0+2] = h2f(hv.z); SV[el][si0+3] = h2f(hv.w);
        }
        __syncthreads();
        float o[4][4] = {};
        for (int e = 0; e < 64; ++e) {
            float4 p4 = *(const float4*)&SP[e][ty*4];
            float4 v4 = *(const float4*)&SV[e][tx*4];
            float p[4] = {p4.x, p4.y, p4.z, p4.w};
            float v[4] = {v4.x, v4.y, v4.z, v4.w};
            #pragma unroll
            for (int i = 0; i < 4; ++i)
                #pragma unroll
                for (int j = 0; j < 4; ++j)
                    o[i][j] += p[i] * v[j];
        }
        #pragma unroll
        for (int i = 0; i < 4; ++i) {
            float4 w4 = make_float4(o[i][0], o[i][1], o[i][2], o[i][3]);
            size_t oidx = (((size_t)h*64 + ty*4 + i)*4 + b) * SEQ + s0 + tx*4;
            *(float4*)&out[oidx] = w4;
        }
    }
}

// ---------------- launcher ----------------
extern "C" void kernel_launch(void* const* d_in, const int* in_sizes, int n_in,
                              void* d_out, int out_size, void* d_ws, size_t ws_size,
                              hipStream_t stream)
{
    const float* x    = (const float*)d_in[0];
    const float* W    = (const float*)d_in[1];
    const float* bias = (const float*)d_in[2];
    float* out = (float*)d_out;

    // workspace: q f32 | k f32 | v f16 | x_hi f16 (aliased later by partial+Pt) | W f16 | [x_lo f16]
    char* p = (char*)d_ws;
    float*  qarr = (float*)p;   p += (size_t)64 * 64 * SEQ * 4;   // 67.1 MB
    float*  karr = (float*)p;   p += (size_t)64 * 64 * SEQ * 4;   // 67.1 MB
    ushort* varr = (ushort*)p;  p += (size_t)64 * 64 * SEQ * 2;   // 33.6 MB
    ushort* xh   = (ushort*)p;
    float*  partial = (float*)xh;                                  // alias (used after GEMM)
    float*  Pt      = (float*)((char*)xh + (size_t)64*NCHUNK*4096*4);
    p += (size_t)BS * D_MODEL * 2;                                 // 33.6 MB
    ushort* Wh   = (ushort*)p;  p += (size_t)QKV_N * D_MODEL * 2;  //  6.3 MB
    ushort* xlo  = (ushort*)p;                                     // 33.6 MB if present

    const size_t need2 = (size_t)p - (size_t)d_ws + (size_t)BS * D_MODEL * 2;
    const int nphase = (ws_size >= need2) ? 2 : 1;

    const int nx = BS * D_MODEL;       // 16777216
    const int nw = QKV_N * D_MODEL;    // 3145728
    cvt_x_f16<<<nx/2048, 256, 0, stream>>>(x, xh, xlo, nphase - 1);
    cvt_w_f16<<<nw/2048, 256, 0, stream>>>(W, Wh);

    qkv_gemm_f16<<<dim3(QKV_N/128, BS/128), 256, 0, stream>>>(
        xh, xlo, Wh, bias, qarr, karr, varr, nphase);

    rope_kernel<<<512, 256, 0, stream>>>(qarr, karr);
    scores_partial<<<dim3(64, NCHUNK), 256, 0, stream>>>(qarr, karr, partial);
    softmax_k<<<64, 64, 0, stream>>>(partial, Pt);
    attn_out<<<dim3(64, NCHUNK), 256, 0, stream>>>(varr, Pt, out);
}

// Round 4
// 335.551 us; speedup vs baseline: 4.5172x; 1.4222x over previous
//
#include <hip/hip_runtime.h>
#include <stdint.h>

#define D_MODEL 1024
#define N_HEADS 16
#define D_HEAD  64
#define BATCH   4
#define SEQ     4096
#define BS      (BATCH*SEQ)     // 16384
#define QKV_N   (3*D_MODEL)     // 3072
#define HB      (N_HEADS*BATCH) // 64

using f16x8 = __attribute__((ext_vector_type(8))) _Float16;
using f32x4 = __attribute__((ext_vector_type(4))) float;

__device__ static inline ushort f2h(float f) {
    _Float16 h = (_Float16)f; ushort u; __builtin_memcpy(&u, &h, 2); return u;
}
__device__ static inline float h2f(ushort u) {
    _Float16 h; __builtin_memcpy(&h, &u, 2); return (float)h;
}
__device__ static inline void async16(const ushort* g, ushort* l) {
    __builtin_amdgcn_global_load_lds(
        (const __attribute__((address_space(1))) void*)g,
        (__attribute__((address_space(3))) void*)l, 16, 0, 0);
}

// ---------------- K0: fp32 -> fp16 ----------------
__global__ __launch_bounds__(256)
void cvt_f16(const float* __restrict__ in, ushort* __restrict__ outp)
{
    int i = (blockIdx.x * 256 + threadIdx.x) * 8;
    float4 a = *(const float4*)(in + i);
    float4 b = *(const float4*)(in + i + 4);
    *(ushort4*)(outp + i)     = make_ushort4(f2h(a.x),f2h(a.y),f2h(a.z),f2h(a.w));
    *(ushort4*)(outp + i + 4) = make_ushort4(f2h(b.x),f2h(b.y),f2h(b.z),f2h(b.w));
}

// ---------------- K1: qkv GEMM via fp16 MFMA, fp32 acc ----------------
// q,k -> fp16 [h*4+b][ci][s]; v -> fp16 [h*4+b][s][e].
__global__ __launch_bounds__(256)
void qkv_gemm_f16(const ushort* __restrict__ Ah, const ushort* __restrict__ Bh,
                  const float* __restrict__ bias,
                  ushort* __restrict__ qh, ushort* __restrict__ kh,
                  ushort* __restrict__ varr)
{
    __shared__ ushort sA[128 * 32];   // 8 KB
    __shared__ ushort sB[128 * 32];   // 8 KB
    const int t = threadIdx.x;
    const int lane = t & 63, w = t >> 6;
    const int m0 = blockIdx.y * 128, n0 = blockIdx.x * 128;

    const int ar0 = (w*2 + 0) * 16 + (lane >> 2);
    const int ar1 = (w*2 + 1) * 16 + (lane >> 2);
    const int kc  = (lane & 3) * 8;
    const ushort* gA0 = Ah + (size_t)(m0 + ar0) * D_MODEL + kc;
    const ushort* gA1 = Ah + (size_t)(m0 + ar1) * D_MODEL + kc;
    const ushort* gB0 = Bh + (size_t)(n0 + ar0) * D_MODEL + kc;
    const ushort* gB1 = Bh + (size_t)(n0 + ar1) * D_MODEL + kc;
    ushort* lA0 = &sA[(w*2 + 0) * 512];
    ushort* lA1 = &sA[(w*2 + 1) * 512];
    ushort* lB0 = &sB[(w*2 + 0) * 512];
    ushort* lB1 = &sB[(w*2 + 1) * 512];

    const int wm = (w >> 1) * 64, wn = (w & 1) * 64;
    const int fr = lane & 15, fq = (lane >> 4) * 8;

    f32x4 acc[4][4] = {};

    for (int k0 = 0; k0 < D_MODEL; k0 += 32) {
        __syncthreads();
        async16(gA0, lA0); async16(gA1, lA1);
        async16(gB0, lB0); async16(gB1, lB1);
        gA0 += 32; gA1 += 32; gB0 += 32; gB1 += 32;
        __syncthreads();

        f16x8 af[4], bf[4];
        #pragma unroll
        for (int i = 0; i < 4; ++i)
            af[i] = *(const f16x8*)&sA[(wm + i*16 + fr) * 32 + fq];
        #pragma unroll
        for (int j = 0; j < 4; ++j)
            bf[j] = *(const f16x8*)&sB[(wn + j*16 + fr) * 32 + fq];
        #pragma unroll
        for (int i = 0; i < 4; ++i)
            #pragma unroll
            for (int j = 0; j < 4; ++j)
                acc[i][j] = __builtin_amdgcn_mfma_f32_16x16x32_f16(
                                af[i], bf[j], acc[i][j], 0, 0, 0);
    }

    // epilogue: C/D row=(lane>>4)*4+r, col=lane&15 (validated r3)
    const int col = lane & 15, rq = (lane >> 4) * 4;
    const int cgb  = n0 + wn;            // 64-aligned
    const int h    = cgb / 192;
    const int type = (cgb % 192) / 64;   // 0=q, 1=k, 2=v
    const int b    = m0 >> 12;
    const int sb   = (m0 & 4095) + wm;

    if (type < 2) {
        ushort* dst = type ? kh : qh;
        #pragma unroll
        for (int j = 0; j < 4; ++j) {
            const int ci = j*16 + col;
            const float bj = bias[cgb + ci];
            const size_t rowoff = ((size_t)(h*4 + b)*64 + ci) * SEQ;
            #pragma unroll
            for (int i = 0; i < 4; ++i) {
                const int s0 = sb + i*16 + rq;
                *(ushort4*)&dst[rowoff + s0] = make_ushort4(
                    f2h(acc[i][j][0] + bj), f2h(acc[i][j][1] + bj),
                    f2h(acc[i][j][2] + bj), f2h(acc[i][j][3] + bj));
            }
        }
    } else {
        #pragma unroll
        for (int j = 0; j < 4; ++j) {
            const int ci = j*16 + col;
            const float bj = bias[cgb + ci];
            #pragma unroll
            for (int i = 0; i < 4; ++i) {
                const int s0 = sb + i*16 + rq;
                #pragma unroll
                for (int r = 0; r < 4; ++r)
                    varr[((size_t)(h*4 + b)*SEQ + s0 + r)*64 + ci] =
                        f2h(acc[i][j][r] + bj);
            }
        }
    }
}

// ---------------- K2: in-place RoPE on fp16 q,k ----------------
__global__ __launch_bounds__(256)
void rope_f16(ushort* __restrict__ qh, ushort* __restrict__ kh)
{
    int tid = blockIdx.x * 256 + threadIdx.x;   // 131072
    int m  = tid & 15;
    int ci = (tid >> 4) & 63;
    int b  = (tid >> 10) & 3;
    int h  = (tid >> 12) & 15;
    ushort* base = (tid >> 16) ? kh : qh;

    float invf = powf(10000.0f, -(float)m / 16.0f);
    float f = (float)ci * invf;
    float cs = cosf(f), sn = sinf(f);

    ushort* p = base + ((size_t)((h*4 + b)*64 + ci)) * SEQ + 2*m;
    float e0 = h2f(p[0]), e1 = h2f(p[1]);
    p[0] = f2h(e0*cs - e1*sn);
    p[1] = f2h(e1*cs + e0*sn);
}

// ---------------- K3: fused scores (MFMA) + softmax; P fp16 [d][e] ----------------
__global__ __launch_bounds__(256)
void scores_softmax(const ushort* __restrict__ qh, const ushort* __restrict__ kh,
                    ushort* __restrict__ Pt)
{
    __shared__ float L[4 * 64 * 64];   // 64 KB: per-wave 64x64 partials
    const int t = threadIdx.x, lane = t & 63, w = t >> 6;
    const int hb = blockIdx.x;
    const ushort* qb = qh + (size_t)hb * 64 * SEQ;
    const ushort* kb = kh + (size_t)hb * 64 * SEQ;
    const int fr = lane & 15, fq = (lane >> 4) * 8;

    f32x4 acc[4][4] = {};
    const int kbase = w * 1024;
    for (int kk = 0; kk < 1024; kk += 32) {
        const int k0 = kbase + kk;
        f16x8 af[4], bf[4];
        #pragma unroll
        for (int i = 0; i < 4; ++i)
            af[i] = *(const f16x8*)&qb[(size_t)(i*16 + fr) * SEQ + k0 + fq];
        #pragma unroll
        for (int j = 0; j < 4; ++j)
            bf[j] = *(const f16x8*)&kb[(size_t)(j*16 + fr) * SEQ + k0 + fq];
        #pragma unroll
        for (int i = 0; i < 4; ++i)
            #pragma unroll
            for (int j = 0; j < 4; ++j)
                acc[i][j] = __builtin_amdgcn_mfma_f32_16x16x32_f16(
                                af[i], bf[j], acc[i][j], 0, 0, 0);
    }

    float* Lw = &L[w * 4096];
    const int col = lane & 15, rq = (lane >> 4) * 4;
    #pragma unroll
    for (int i = 0; i < 4; ++i)
        #pragma unroll
        for (int j = 0; j < 4; ++j)
            #pragma unroll
            for (int r = 0; r < 4; ++r)
                Lw[(i*16 + rq + r)*64 + j*16 + col] = acc[i][j][r];
    __syncthreads();

    // reduce 4 partials into L[0..4095]
    #pragma unroll
    for (int u = 0; u < 16; ++u) {
        int idx = t*16 + u;
        L[idx] = L[idx] + L[4096 + idx] + L[8192 + idx] + L[12288 + idx];
    }
    __syncthreads();

    // softmax over e for each row d (threads 0..63)
    if (t < 64) {
        float* row = &L[t * 64];
        float mx = -1e30f;
        for (int e = 0; e < 64; ++e) mx = fmaxf(mx, row[e]);
        float sum = 0.f;
        for (int e = 0; e < 64; ++e) {
            float v = expf(0.125f * (row[e] - mx));
            row[e] = v; sum += v;
        }
        float inv = 1.f / sum;
        ushort* pd = Pt + (size_t)hb * 4096 + t * 64;
        for (int e = 0; e < 64; ++e) pd[e] = f2h(row[e] * inv);
    }
}

// ---------------- K4: out[d][s] = sum_e P[d][e] * v[s][e]  (MFMA, K=64) ----------------
__global__ __launch_bounds__(256)
void attn_out_mfma(const ushort* __restrict__ varr, const ushort* __restrict__ Pt,
                   float* __restrict__ out)
{
    const int t = threadIdx.x, lane = t & 63, w = t >> 6;
    const int hb = blockIdx.x;
    const int sbase = blockIdx.y * 256 + w * 64;
    const int fr = lane & 15, fq = (lane >> 4) * 8;

    const ushort* Pb = Pt + (size_t)hb * 4096;
    const ushort* vb = varr + (size_t)hb * SEQ * 64;

    f16x8 aP[4][2], bV[4][2];
    #pragma unroll
    for (int i = 0; i < 4; ++i)
        #pragma unroll
        for (int ks = 0; ks < 2; ++ks)
            aP[i][ks] = *(const f16x8*)&Pb[(i*16 + fr)*64 + ks*32 + fq];
    #pragma unroll
    for (int j = 0; j < 4; ++j)
        #pragma unroll
        for (int ks = 0; ks < 2; ++ks)
            bV[j][ks] = *(const f16x8*)&vb[(size_t)(sbase + j*16 + fr)*64 + ks*32 + fq];

    f32x4 acc[4][4] = {};
    #pragma unroll
    for (int ks = 0; ks < 2; ++ks)
        #pragma unroll
        for (int i = 0; i < 4; ++i)
            #pragma unroll
            for (int j = 0; j < 4; ++j)
                acc[i][j] = __builtin_amdgcn_mfma_f32_16x16x32_f16(
                                aP[i][ks], bV[j][ks], acc[i][j], 0, 0, 0);

    const int col = lane & 15, rq = (lane >> 4) * 4;
    const int h = hb >> 2, b = hb & 3;
    #pragma unroll
    for (int i = 0; i < 4; ++i)
        #pragma unroll
        for (int j = 0; j < 4; ++j)
            #pragma unroll
            for (int r = 0; r < 4; ++r)
                out[(((size_t)h*64 + i*16 + rq + r)*4 + b)*SEQ + sbase + j*16 + col]
                    = acc[i][j][r];
}

// ---------------- launcher ----------------
extern "C" void kernel_launch(void* const* d_in, const int* in_sizes, int n_in,
                              void* d_out, int out_size, void* d_ws, size_t ws_size,
                              hipStream_t stream)
{
    const float* x    = (const float*)d_in[0];
    const float* W    = (const float*)d_in[1];
    const float* bias = (const float*)d_in[2];
    float* out = (float*)d_out;

    char* p = (char*)d_ws;
    ushort* qh   = (ushort*)p;  p += (size_t)HB * 64 * SEQ * 2;   // 33.6 MB
    ushort* kh   = (ushort*)p;  p += (size_t)HB * 64 * SEQ * 2;   // 33.6 MB
    ushort* varr = (ushort*)p;  p += (size_t)HB * SEQ * 64 * 2;   // 33.6 MB
    ushort* Pth  = (ushort*)p;  p += (size_t)HB * 4096 * 2;       //  0.5 MB
    ushort* xh   = (ushort*)p;  p += (size_t)BS * D_MODEL * 2;    // 33.6 MB
    ushort* Wh   = (ushort*)p;  p += (size_t)QKV_N * D_MODEL * 2; //  6.3 MB

    const int nx = BS * D_MODEL;
    const int nw = QKV_N * D_MODEL;
    cvt_f16<<<nx/2048, 256, 0, stream>>>(x, xh);
    cvt_f16<<<nw/2048, 256, 0, stream>>>(W, Wh);

    qkv_gemm_f16<<<dim3(QKV_N/128, BS/128), 256, 0, stream>>>(
        xh, Wh, bias, qh, kh, varr);

    rope_f16<<<512, 256, 0, stream>>>(qh, kh);
    scores_softmax<<<64, 256, 0, stream>>>(qh, kh, Pth);
    attn_out_mfma<<<dim3(64, 16), 256, 0, stream>>>(varr, Pth, out);
}

// Round 5
// 319.549 us; speedup vs baseline: 4.7434x; 1.0501x over previous
//
#include <hip/hip_runtime.h>
#include <stdint.h>

#define D_MODEL 1024
#define N_HEADS 16
#define D_HEAD  64
#define BATCH   4
#define SEQ     4096
#define BS      (BATCH*SEQ)     // 16384
#define QKV_N   (3*D_MODEL)     // 3072
#define HB      (N_HEADS*BATCH) // 64
#define NCHUNK  8
#define CH_S    (SEQ/NCHUNK)    // 512

using f16x8 = __attribute__((ext_vector_type(8))) _Float16;
using f32x4 = __attribute__((ext_vector_type(4))) float;

__device__ static inline ushort f2h(float f) {
    _Float16 h = (_Float16)f; ushort u; __builtin_memcpy(&u, &h, 2); return u;
}
__device__ static inline float h2f(ushort u) {
    _Float16 h; __builtin_memcpy(&h, &u, 2); return (float)h;
}
__device__ static inline void async16(const ushort* g, ushort* l) {
    __builtin_amdgcn_global_load_lds(
        (const __attribute__((address_space(1))) void*)g,
        (__attribute__((address_space(3))) void*)l, 16, 0, 0);
}

// ---------------- K0: fp32 -> fp16 for x and W in one launch ----------------
__global__ __launch_bounds__(256)
void cvt_both(const float* __restrict__ x, const float* __restrict__ W,
              ushort* __restrict__ xh, ushort* __restrict__ Wh, int nx)
{
    int i = (blockIdx.x * 256 + threadIdx.x) * 8;
    const float* src; ushort* dst; int o;
    if (i < nx) { src = x; dst = xh; o = i; }
    else        { src = W; dst = Wh; o = i - nx; }
    float4 a = *(const float4*)(src + o);
    float4 b = *(const float4*)(src + o + 4);
    *(ushort4*)(dst + o)     = make_ushort4(f2h(a.x),f2h(a.y),f2h(a.z),f2h(a.w));
    *(ushort4*)(dst + o + 4) = make_ushort4(f2h(b.x),f2h(b.y),f2h(b.z),f2h(b.w));
}

// ---------------- K1: qkv GEMM via fp16 MFMA, fp32 acc, fused RoPE ----------------
// q,k -> fp16 [h*4+b][ci][s] (RoPE applied inline for s<32); v -> fp16 [h*4+b][s][e].
__global__ __launch_bounds__(256)
void qkv_gemm_f16(const ushort* __restrict__ Ah, const ushort* __restrict__ Bh,
                  const float* __restrict__ bias,
                  ushort* __restrict__ qh, ushort* __restrict__ kh,
                  ushort* __restrict__ varr)
{
    __shared__ ushort sA[128 * 32];   // 8 KB
    __shared__ ushort sB[128 * 32];   // 8 KB
    const int t = threadIdx.x;
    const int lane = t & 63, w = t >> 6;
    const int m0 = blockIdx.y * 128, n0 = blockIdx.x * 128;

    const int ar0 = (w*2 + 0) * 16 + (lane >> 2);
    const int ar1 = (w*2 + 1) * 16 + (lane >> 2);
    const int kc  = (lane & 3) * 8;
    const ushort* gA0 = Ah + (size_t)(m0 + ar0) * D_MODEL + kc;
    const ushort* gA1 = Ah + (size_t)(m0 + ar1) * D_MODEL + kc;
    const ushort* gB0 = Bh + (size_t)(n0 + ar0) * D_MODEL + kc;
    const ushort* gB1 = Bh + (size_t)(n0 + ar1) * D_MODEL + kc;
    ushort* lA0 = &sA[(w*2 + 0) * 512];
    ushort* lA1 = &sA[(w*2 + 1) * 512];
    ushort* lB0 = &sB[(w*2 + 0) * 512];
    ushort* lB1 = &sB[(w*2 + 1) * 512];

    const int wm = (w >> 1) * 64, wn = (w & 1) * 64;
    const int fr = lane & 15, fq = (lane >> 4) * 8;

    f32x4 acc[4][4] = {};

    for (int k0 = 0; k0 < D_MODEL; k0 += 32) {
        __syncthreads();
        async16(gA0, lA0); async16(gA1, lA1);
        async16(gB0, lB0); async16(gB1, lB1);
        gA0 += 32; gA1 += 32; gB0 += 32; gB1 += 32;
        __syncthreads();

        f16x8 af[4], bf[4];
        #pragma unroll
        for (int i = 0; i < 4; ++i)
            af[i] = *(const f16x8*)&sA[(wm + i*16 + fr) * 32 + fq];
        #pragma unroll
        for (int j = 0; j < 4; ++j)
            bf[j] = *(const f16x8*)&sB[(wn + j*16 + fr) * 32 + fq];
        #pragma unroll
        for (int i = 0; i < 4; ++i)
            #pragma unroll
            for (int j = 0; j < 4; ++j)
                acc[i][j] = __builtin_amdgcn_mfma_f32_16x16x32_f16(
                                af[i], bf[j], acc[i][j], 0, 0, 0);
    }

    // epilogue: C/D row=(lane>>4)*4+r, col=lane&15 (validated r3/r4)
    const int col = lane & 15, rq = (lane >> 4) * 4;
    const int cgb  = n0 + wn;            // 64-aligned
    const int h    = cgb / 192;
    const int type = (cgb % 192) / 64;   // 0=q, 1=k, 2=v
    const int b    = m0 >> 12;
    const int sb   = (m0 & 4095) + wm;

    if (type < 2) {
        ushort* dst = type ? kh : qh;
        #pragma unroll
        for (int j = 0; j < 4; ++j) {
            const int ci = j*16 + col;
            const float bj = bias[cgb + ci];
            const size_t rowoff = ((size_t)(h*4 + b)*64 + ci) * SEQ;
            #pragma unroll
            for (int i = 0; i < 4; ++i) {
                const int s0 = sb + i*16 + rq;            // multiple of 4
                float v0 = acc[i][j][0] + bj, v1 = acc[i][j][1] + bj;
                float v2 = acc[i][j][2] + bj, v3 = acc[i][j][3] + bj;
                if (s0 < 32) {
                    // RoPE: pairs (s0,s0+1) m=s0/2 and (s0+2,s0+3) m=s0/2+1,
                    // angle = ci * 10000^(-m/16)
                    int mp = s0 >> 1;
                    float if0 = powf(10000.0f, -(float)mp / 16.0f);
                    float if1 = powf(10000.0f, -(float)(mp + 1) / 16.0f);
                    float a0 = (float)ci * if0, a1 = (float)ci * if1;
                    float c0 = cosf(a0), s0n = sinf(a0);
                    float c1 = cosf(a1), s1n = sinf(a1);
                    float n0 = v0*c0 - v1*s0n, n1 = v1*c0 + v0*s0n;
                    float n2 = v2*c1 - v3*s1n, n3 = v3*c1 + v2*s1n;
                    v0 = n0; v1 = n1; v2 = n2; v3 = n3;
                }
                *(ushort4*)&dst[rowoff + s0] = make_ushort4(
                    f2h(v0), f2h(v1), f2h(v2), f2h(v3));
            }
        }
    } else {
        #pragma unroll
        for (int j = 0; j < 4; ++j) {
            const int ci = j*16 + col;
            const float bj = bias[cgb + ci];
            #pragma unroll
            for (int i = 0; i < 4; ++i) {
                const int s0 = sb + i*16 + rq;
                #pragma unroll
                for (int r = 0; r < 4; ++r)
                    varr[((size_t)(h*4 + b)*SEQ + s0 + r)*64 + ci] =
                        f2h(acc[i][j][r] + bj);
            }
        }
    }
}

// ---------------- K2: partial scores (MFMA) per K-chunk ----------------
// partial[hb][chunk][d][e] = sum_{s in chunk} q[d,s]*k[e,s]
__global__ __launch_bounds__(256)
void scores_partial(const ushort* __restrict__ qh, const ushort* __restrict__ kh,
                    float* __restrict__ partial)
{
    __shared__ float L[4 * 4096];   // 64 KB: per-wave 64x64 partials
    const int t = threadIdx.x, lane = t & 63, w = t >> 6;
    const int hb = blockIdx.x, chunk = blockIdx.y;
    const ushort* qb = qh + (size_t)hb * 64 * SEQ;
    const ushort* kb = kh + (size_t)hb * 64 * SEQ;
    const int fr = lane & 15, fq = (lane >> 4) * 8;

    f32x4 acc[4][4] = {};
    const int kbase = chunk * CH_S + w * (CH_S / 4);
    for (int kk = 0; kk < CH_S / 4; kk += 32) {
        const int k0 = kbase + kk;
        f16x8 af[4], bf[4];
        #pragma unroll
        for (int i = 0; i < 4; ++i)
            af[i] = *(const f16x8*)&qb[(size_t)(i*16 + fr) * SEQ + k0 + fq];
        #pragma unroll
        for (int j = 0; j < 4; ++j)
            bf[j] = *(const f16x8*)&kb[(size_t)(j*16 + fr) * SEQ + k0 + fq];
        #pragma unroll
        for (int i = 0; i < 4; ++i)
            #pragma unroll
            for (int j = 0; j < 4; ++j)
                acc[i][j] = __builtin_amdgcn_mfma_f32_16x16x32_f16(
                                af[i], bf[j], acc[i][j], 0, 0, 0);
    }

    float* Lw = &L[w * 4096];
    const int col = lane & 15, rq = (lane >> 4) * 4;
    #pragma unroll
    for (int i = 0; i < 4; ++i)
        #pragma unroll
        for (int j = 0; j < 4; ++j)
            #pragma unroll
            for (int r = 0; r < 4; ++r)
                Lw[(i*16 + rq + r)*64 + j*16 + col] = acc[i][j][r];
    __syncthreads();

    // reduce 4 wave-partials and write to global (float4, coalesced)
    float* pb = partial + ((size_t)hb * NCHUNK + chunk) * 4096;
    #pragma unroll
    for (int u = 0; u < 4; ++u) {
        int idx = u*1024 + t*4;
        f32x4 s = *(f32x4*)&L[idx];
        s += *(f32x4*)&L[4096 + idx];
        s += *(f32x4*)&L[8192 + idx];
        s += *(f32x4*)&L[12288 + idx];
        *(f32x4*)&pb[idx] = s;
    }
}

// ---------------- K3: sum chunks, softmax over e; P fp16 [d][e] ----------------
__global__ __launch_bounds__(256)
void softmax_k(const float* __restrict__ partial, ushort* __restrict__ Pt)
{
    __shared__ float L[64 * 65];   // padded: row d at L[d*65]
    const int t = threadIdx.x;
    const int hb = blockIdx.x;
    const float* pb = partial + (size_t)hb * NCHUNK * 4096;

    #pragma unroll
    for (int u = 0; u < 16; ++u) {
        int idx = u*256 + t;              // coalesced global reads
        float s = 0.f;
        #pragma unroll
        for (int c = 0; c < NCHUNK; ++c) s += pb[c*4096 + idx];
        L[(idx >> 6) * 65 + (idx & 63)] = s;
    }
    __syncthreads();

    if (t < 64) {
        float* row = &L[t * 65];          // stride 65: conflict-free across lanes
        float mx = -1e30f;
        for (int e = 0; e < 64; ++e) mx = fmaxf(mx, row[e]);
        float sum = 0.f;
        for (int e = 0; e < 64; ++e) {
            float v = expf(0.125f * (row[e] - mx));
            row[e] = v; sum += v;
        }
        float inv = 1.f / sum;
        ushort* pd = Pt + (size_t)hb * 4096 + t * 64;
        for (int e = 0; e < 64; ++e) pd[e] = f2h(row[e] * inv);
    }
}

// ---------------- K4: out^T[s][d] = sum_e v[s][e] * P[d][e]  (MFMA, K=64) ----------------
__global__ __launch_bounds__(256)
void attn_out_mfma(const ushort* __restrict__ varr, const ushort* __restrict__ Pt,
                   float* __restrict__ out)
{
    const int t = threadIdx.x, lane = t & 63, w = t >> 6;
    const int hb = blockIdx.x;
    const int sb = blockIdx.y * 256 + w * 64;
    const int fr = lane & 15, fq = (lane >> 4) * 8;

    const ushort* Pb = Pt + (size_t)hb * 4096;
    const ushort* vb = varr + (size_t)hb * SEQ * 64;

    f16x8 aV[4][2], bP[4][2];
    #pragma unroll
    for (int i = 0; i < 4; ++i)
        #pragma unroll
        for (int ks = 0; ks < 2; ++ks)
            aV[i][ks] = *(const f16x8*)&vb[(size_t)(sb + i*16 + fr)*64 + ks*32 + fq];
    #pragma unroll
    for (int j = 0; j < 4; ++j)
        #pragma unroll
        for (int ks = 0; ks < 2; ++ks)
            bP[j][ks] = *(const f16x8*)&Pb[(j*16 + fr)*64 + ks*32 + fq];

    f32x4 acc[4][4] = {};   // [s-tile][d-tile]
    #pragma unroll
    for (int ks = 0; ks < 2; ++ks)
        #pragma unroll
        for (int i = 0; i < 4; ++i)
            #pragma unroll
            for (int j = 0; j < 4; ++j)
                acc[i][j] = __builtin_amdgcn_mfma_f32_16x16x32_f16(
                                aV[i][ks], bP[j][ks], acc[i][j], 0, 0, 0);

    // D[m=s][n=d]: regs r are 4 consecutive s -> float4 stores along s
    const int col = lane & 15, rq = (lane >> 4) * 4;
    const int h = hb >> 2, b = hb & 3;
    #pragma unroll
    for (int i = 0; i < 4; ++i)
        #pragma unroll
        for (int j = 0; j < 4; ++j) {
            const int dg = j*16 + col;
            size_t off = (((size_t)h*64 + dg)*4 + b)*SEQ + sb + i*16 + rq;
            *(float4*)&out[off] = make_float4(acc[i][j][0], acc[i][j][1],
                                              acc[i][j][2], acc[i][j][3]);
        }
}

// ---------------- launcher ----------------
extern "C" void kernel_launch(void* const* d_in, const int* in_sizes, int n_in,
                              void* d_out, int out_size, void* d_ws, size_t ws_size,
                              hipStream_t stream)
{
    const float* x    = (const float*)d_in[0];
    const float* W    = (const float*)d_in[1];
    const float* bias = (const float*)d_in[2];
    float* out = (float*)d_out;

    char* p = (char*)d_ws;
    ushort* qh   = (ushort*)p;  p += (size_t)HB * 64 * SEQ * 2;        // 33.6 MB
    ushort* kh   = (ushort*)p;  p += (size_t)HB * 64 * SEQ * 2;        // 33.6 MB
    ushort* varr = (ushort*)p;  p += (size_t)HB * SEQ * 64 * 2;        // 33.6 MB
    ushort* Pth  = (ushort*)p;  p += (size_t)HB * 4096 * 2;            //  0.5 MB
    float* partial = (float*)p; p += (size_t)HB * NCHUNK * 4096 * 4;   //  8.4 MB
    ushort* xh   = (ushort*)p;  p += (size_t)BS * D_MODEL * 2;         // 33.6 MB
    ushort* Wh   = (ushort*)p;  p += (size_t)QKV_N * D_MODEL * 2;      //  6.3 MB

    const int nx = BS * D_MODEL;       // 16777216
    const int nw = QKV_N * D_MODEL;    // 3145728
    cvt_both<<<(nx + nw)/2048, 256, 0, stream>>>(x, W, xh, Wh, nx);

    qkv_gemm_f16<<<dim3(QKV_N/128, BS/128), 256, 0, stream>>>(
        xh, Wh, bias, qh, kh, varr);

    scores_partial<<<dim3(HB, NCHUNK), 256, 0, stream>>>(qh, kh, partial);
    softmax_k<<<HB, 256, 0, stream>>>(partial, Pth);
    attn_out_mfma<<<dim3(HB, 16), 256, 0, stream>>>(varr, Pth, out);
}